// Round 13
// baseline (103.098 us; speedup 1.0000x reference)
//
#include <hip/hip_runtime.h>
#include <math.h>
#include <type_traits>

#define N 8192
#define BIT 32
#define NCLASS 100
#define ALPHA 0.1
#define BEITA 1.0
#define GAMMA 0.1

#define BT 128                      // pair tile 128x128
#define NT (N / BT)                 // 64 tile-rows
#define NPAIRBLK (NT * (NT + 1) / 2)   // 2080
#define NPREP (N / 8)               // 1024 prep blocks, 8 rows each

typedef __attribute__((ext_vector_type(8))) short s16x8;   // 8 bf16 (4 VGPRs)
typedef __attribute__((ext_vector_type(4))) float f32x4;   // MFMA accum

#define RSQRT2 0.70710678118654752f

// pack two pre-scaled floats' bf16 (round-half-up) into one u32: lo=x, hi=y
static __device__ __forceinline__ unsigned int pk_bf(float x, float y) {
    unsigned int bx = __float_as_uint(x) + 0x8000u;
    unsigned int by = __float_as_uint(y) + 0x8000u;
    return __builtin_amdgcn_perm(by, bx, 0x07060302u);   // [by.hi16 : bx.hi16]
}

// ws layout (bytes) — everything written unconditionally every call, NO memset needed:
//   [1024..33791]   int labels[N]
//   [40960..57599]  double Ppos[2080]
//   [61440..78079]  double Pneg[2080]
//   [81920..]       double Pc[1024]
//   [90112..]       double Pm[1024]
//   [98304..]       double Pb[1024]

// ---------------- prep: labels + cls + quant/bal -> per-block partials (no atomics) ----
__global__ __launch_bounds__(256) void prep_kernel(
    const float* __restrict__ u, const float* __restrict__ Y, const float* __restrict__ y,
    int* __restrict__ labels, double* __restrict__ Pc, double* __restrict__ Pm,
    double* __restrict__ Pb)
{
    const int t = threadIdx.x;
    const int lane = t & 63;
    const int w = t >> 6;
    const int row0 = blockIdx.x * 8;             // block owns 8 rows

    // ---- cls + labels: wave w handles rows row0 + 2w, row0 + 2w + 1
    float wcls = 0.f;
    #pragma unroll
    for (int rr = 0; rr < 2; ++rr) {
        const int r = row0 + w * 2 + rr;
        const float* Yp = Y + (size_t)r * NCLASS;
        const float* yp = y + (size_t)r * NCLASS;
        const bool has2 = lane < (NCLASS - 64);
        float Y0 = Yp[lane];
        float Y1 = has2 ? Yp[64 + lane] : -1e30f;
        float y0 = yp[lane];
        float y1 = has2 ? yp[64 + lane] : 0.f;
        float m = fmaxf(Y0, Y1);
        #pragma unroll
        for (int o = 32; o; o >>= 1) m = fmaxf(m, __shfl_xor(m, o, 64));
        float e  = __expf(Y0 - m) + (has2 ? __expf(Y1 - m) : 0.f);
        float tg = y0 * Y0 + (has2 ? y1 * Y1 : 0.f);
        #pragma unroll
        for (int o = 32; o; o >>= 1) { e += __shfl_xor(e, o, 64); tg += __shfl_xor(tg, o, 64); }
        unsigned long long b0 = __ballot(y0 > 0.5f);
        unsigned long long b1 = __ballot(has2 && (y1 > 0.5f));
        if (lane == 0) {
            int lbl = b0 ? (__ffsll((long long)b0) - 1) : (64 + __ffsll((long long)b1) - 1);
            labels[r] = lbl;
            wcls += m + __logf(e) - tg;
        }
    }

    // ---- u: quant + bal. thread t owns float t of the block's 256-float chunk
    const float x = u[(size_t)row0 * BIT + t];
    float bb = (x > 0.f) ? 1.f : ((x < 0.f) ? -1.f : 0.f);  // jnp.sign
    float d = x - bb;
    float bal = d * d;
    float rs = x;
    #pragma unroll
    for (int o = 1; o < 32; o <<= 1) rs += __shfl_xor(rs, o, 64);  // 32 lanes = one u row
    float mrow = rs * (1.f / BIT);
    float m2 = ((t & 31) == 0) ? mrow * mrow : 0.f;
    #pragma unroll
    for (int o = 32; o; o >>= 1) { m2 += __shfl_down(m2, o, 64); bal += __shfl_down(bal, o, 64); }

    __shared__ double red[4][3];
    if (lane == 0) { red[w][0] = (double)wcls; red[w][1] = (double)m2; red[w][2] = (double)bal; }
    __syncthreads();
    if (t == 0) {
        Pc[blockIdx.x] = red[0][0] + red[1][0] + red[2][0] + red[3][0];
        Pm[blockIdx.x] = red[0][1] + red[1][1] + red[2][1] + red[3][1];
        Pb[blockIdx.x] = red[0][2] + red[1][2] + red[2][2] + red[3][2];
    }
}

// ------- pairwise hash loss: bf16 MFMA (pre-scaled => acc IS theta), 128x128 tiles -----
__global__ __launch_bounds__(256, 6) void pair_kernel(
    const float* __restrict__ u, const int* __restrict__ labels,
    double* __restrict__ Ppos, double* __restrict__ Pneg)
{
    // closed-form triangular decode: b -> (ti, tj), ti <= tj
    const int b = blockIdx.x;
    int ti = (int)(((float)(2 * NT + 1) - sqrtf((float)((2 * NT + 1) * (2 * NT + 1) - 8 * b))) * 0.5f);
    int S = ti * (2 * NT - ti + 1) / 2;
    if (S > b) { --ti; S = ti * (2 * NT - ti + 1) / 2; }
    else { int S2 = (ti + 1) * (2 * NT - ti) / 2; if (S2 <= b) { ++ti; S = S2; } }
    const int tj = ti + (b - S);
    const int i0 = ti * BT, j0 = tj * BT;

    __shared__ __align__(16) unsigned short Us[4][256][8];   // 16 KB, conflict-free layout
    __shared__ int Ls[256];
    __shared__ float wredp[4], wredn[4];

    const int t = threadIdx.x;

    // stage: thread t owns staged row t; values pre-scaled by 1/sqrt(2) so that
    // (A*B^T) = u.u^T/2 = theta directly. Round-half-up bf16 via +0x8000 + v_perm.
    {
        const int g = (t < BT) ? (i0 + t) : (j0 + t - BT);
        const float4* p = (const float4*)(u + (size_t)g * BIT);
        #pragma unroll
        for (int c = 0; c < 4; ++c) {
            float4 v0 = p[2 * c], v1 = p[2 * c + 1];
            unsigned int pk[4];
            pk[0] = pk_bf(v0.x * RSQRT2, v0.y * RSQRT2);
            pk[1] = pk_bf(v0.z * RSQRT2, v0.w * RSQRT2);
            pk[2] = pk_bf(v1.x * RSQRT2, v1.y * RSQRT2);
            pk[3] = pk_bf(v1.z * RSQRT2, v1.w * RSQRT2);
            *(uint4*)&Us[c][t][0] = *(uint4*)pk;
        }
        Ls[t] = labels[g];
    }
    __syncthreads();

    const int lane = t & 63;
    const int w = t >> 6;            // wave 0..3, 2x2 wave grid, 64x64 per wave
    const int wy = w >> 1, wx = w & 1;
    const int quad = lane >> 4, lr = lane & 15;

    s16x8 av[4], bv[4];
    #pragma unroll
    for (int x = 0; x < 4; ++x) {
        av[x] = *(const s16x8*)&Us[quad][wy * 64 + x * 16 + lr][0];
        bv[x] = *(const s16x8*)&Us[quad][128 + wx * 64 + x * 16 + lr][0];
    }
    int lbv[4], lav[16];
    #pragma unroll
    for (int c = 0; c < 4; ++c) lbv[c] = Ls[128 + wx * 64 + c * 16 + lr];
    #pragma unroll
    for (int a = 0; a < 4; ++a)
        #pragma unroll
        for (int r = 0; r < 4; ++r) lav[a * 4 + r] = Ls[wy * 64 + a * 16 + quad * 4 + r];

    float sp0 = 0.f, sp1 = 0.f, sn0 = 0.f, sn1 = 0.f;
    auto run = [&](auto DIAGC) {
        constexpr bool DIAG = decltype(DIAGC)::value;
        f32x4 accf[4][4];
        #pragma unroll
        for (int a = 0; a < 4; ++a)
            #pragma unroll
            for (int c = 0; c < 4; ++c)
                accf[a][c] = __builtin_amdgcn_mfma_f32_16x16x32_bf16(
                    av[a], bv[c], (f32x4){0.f, 0.f, 0.f, 0.f}, 0, 0, 0);

        #pragma unroll
        for (int a = 0; a < 4; ++a) {
            #pragma unroll
            for (int c = 0; c < 4; ++c) {
                const int lb = lbv[c];
                #pragma unroll
                for (int r = 0; r < 4; ++r) {
                    const float v = accf[a][c][r];   // = theta; col=lane&15, row=quad*4+reg
                    const bool sim = (lav[a * 4 + r] == lb);
                    float e  = exp2f(-1.44269504f * fabsf(v));
                    float l2 = __log2f(1.f + e);
                    float tp = fmaf(0.69314718f, l2, fmaxf(-v, 0.f)); // softplus(th)-th
                    float tn = tp + v;                                 // softplus(th)
                    if (DIAG) {
                        const int lrow = wy * 64 + a * 16 + quad * 4 + r;
                        const int lcol = wx * 64 + c * 16 + lr;
                        const bool keep = lcol > lrow;   // strict upper triangle
                        tp = keep ? tp : 0.f;
                        tn = keep ? tn : 0.f;
                    }
                    float up = sim ? tp : 0.f;
                    float un = sim ? 0.f : tn;
                    if (r & 1) { sp1 += up; sn1 += un; }
                    else       { sp0 += up; sn0 += un; }
                }
            }
        }
    };
    if (ti == tj) run(std::integral_constant<bool, true>{});
    else          run(std::integral_constant<bool, false>{});

    float sp = sp0 + sp1, sn = sn0 + sn1;
    #pragma unroll
    for (int o = 32; o; o >>= 1) { sp += __shfl_down(sp, o, 64); sn += __shfl_down(sn, o, 64); }
    if (lane == 0) { wredp[w] = sp; wredn[w] = sn; }
    __syncthreads();
    if (t == 0) {
        Ppos[b] = (double)(wredp[0] + wredp[1] + wredp[2] + wredp[3]);
        Pneg[b] = (double)(wredn[0] + wredn[1] + wredn[2] + wredn[3]);
    }
}

// ---------------- finalize: histogram from labels + scales + reduce partials -----------
__global__ __launch_bounds__(256) void fin_kernel(
    const int* __restrict__ labels, const double* __restrict__ Ppos,
    const double* __restrict__ Pneg, const double* __restrict__ Pc,
    const double* __restrict__ Pm, const double* __restrict__ Pb, float* __restrict__ out)
{
    __shared__ int h[128];
    __shared__ double red[4][5];
    __shared__ double scd[2];
    const int t = threadIdx.x;
    const int lane = t & 63;
    const int w = t >> 6;

    if (t < 128) h[t] = 0;
    __syncthreads();
    #pragma unroll
    for (int k = 0; k < 32; ++k) atomicAdd(&h[labels[t + k * 256]], 1);
    __syncthreads();

    if (w == 0) {                 // wave 0: simsum -> scales
        long long c0 = (lane < NCLASS) ? h[lane] : 0;
        long long c1 = (lane + 64 < NCLASS) ? h[lane + 64] : 0;
        long long ss = c0 * c0 + c1 * c1;
        #pragma unroll
        for (int o = 32; o; o >>= 1) ss += __shfl_xor(ss, o, 64);
        if (lane == 0) {
            double s1 = (double)ss - (double)N;
            double s0 = (double)N * (double)N - (double)ss;
            if (s0 == 0.0) s0 = 1.0;
            if (s1 == 0.0) s1 = 1.0;
            double s = s0 + s1;
            scd[0] = s / s1;      // spos
            scd[1] = s / s0;      // sneg
        }
    }

    double p0 = 0, p1 = 0, cc = 0, mm = 0, bb = 0;
    for (int i = t; i < NPAIRBLK; i += 256) { p0 += Ppos[i]; p1 += Pneg[i]; }
    for (int i = t; i < NPREP; i += 256)    { cc += Pc[i]; mm += Pm[i]; bb += Pb[i]; }
    #pragma unroll
    for (int o = 32; o; o >>= 1) {
        p0 += __shfl_down(p0, o, 64); p1 += __shfl_down(p1, o, 64);
        cc += __shfl_down(cc, o, 64); mm += __shfl_down(mm, o, 64);
        bb += __shfl_down(bb, o, 64);
    }
    if (lane == 0) { red[w][0] = p0; red[w][1] = p1; red[w][2] = cc; red[w][3] = mm; red[w][4] = bb; }
    __syncthreads();
    if (t == 0) {
        double a_pos = red[0][0] + red[1][0] + red[2][0] + red[3][0];
        double a_neg = red[0][1] + red[1][1] + red[2][1] + red[3][1];
        double a_cls = red[0][2] + red[1][2] + red[2][2] + red[3][2];
        double a_m2  = red[0][3] + red[1][3] + red[2][3] + red[3][3];
        double a_bal = red[0][4] + red[1][4] + red[2][4] + red[3][4];
        double pairsum = scd[0] * a_pos + scd[1] * a_neg;
        double lik   = 2.0 * pairsum / ((double)N * (double)(N - 1));
        double cls   = a_cls / (double)N;
        double quant = ALPHA * (a_m2 / (double)N);
        double bal   = GAMMA * (a_bal / ((double)N * (double)BIT));
        out[0] = (float)(lik + BEITA * cls + quant + bal);
    }
}

extern "C" void kernel_launch(void* const* d_in, const int* in_sizes, int n_in,
                              void* d_out, int out_size, void* d_ws, size_t ws_size,
                              hipStream_t stream) {
    const float* u = (const float*)d_in[0];   // [N, BIT]
    const float* Y = (const float*)d_in[1];   // [N, NCLASS]
    const float* y = (const float*)d_in[2];   // [N, NCLASS] one-hot
    float* out = (float*)d_out;

    char* ws = (char*)d_ws;
    int*    labels = (int*)(ws + 1024);
    double* Ppos   = (double*)(ws + 40960);
    double* Pneg   = (double*)(ws + 61440);
    double* Pc     = (double*)(ws + 81920);
    double* Pm     = (double*)(ws + 90112);
    double* Pb     = (double*)(ws + 98304);

    // no memset: every ws word consumed is written unconditionally earlier in the chain
    prep_kernel<<<NPREP, 256, 0, stream>>>(u, Y, y, labels, Pc, Pm, Pb);
    pair_kernel<<<NPAIRBLK, 256, 0, stream>>>(u, labels, Ppos, Pneg);
    fin_kernel<<<1, 256, 0, stream>>>(labels, Ppos, Pneg, Pc, Pm, Pb, out);
}

// Round 14
// 98.513 us; speedup vs baseline: 1.0465x; 1.0465x over previous
//
#include <hip/hip_runtime.h>
#include <math.h>
#include <type_traits>

#define N 8192
#define BIT 32
#define NCLASS 100
#define ALPHA 0.1
#define BEITA 1.0
#define GAMMA 0.1

#define BT 128                      // pair tile 128x128
#define NT (N / BT)                 // 64 tile-rows
#define NPAIRBLK (NT * (NT + 1) / 2)   // 2080
#define NPREP (N / 8)               // 1024 prep blocks, 8 rows each

typedef __attribute__((ext_vector_type(8))) short s16x8;   // 8 bf16 (4 VGPRs)
typedef __attribute__((ext_vector_type(4))) float f32x4;   // MFMA accum

// round-to-nearest-even fp32 -> bf16 bits
static __device__ __forceinline__ unsigned short f2bf(float f) {
    unsigned int x = __float_as_uint(f);
    x += 0x7fff + ((x >> 16) & 1);
    return (unsigned short)(x >> 16);
}

// ws layout (bytes) — everything written unconditionally every call, NO memset needed:
//   [1024..33791]   int labels[N]
//   [40960..57599]  double Ppos[2080]
//   [61440..78079]  double Pneg[2080]
//   [81920..]       double Pc[1024]
//   [90112..]       double Pm[1024]
//   [98304..]       double Pb[1024]

// ---------------- prep: labels + cls + quant/bal -> per-block partials (no atomics) ----
__global__ __launch_bounds__(256) void prep_kernel(
    const float* __restrict__ u, const float* __restrict__ Y, const float* __restrict__ y,
    int* __restrict__ labels, double* __restrict__ Pc, double* __restrict__ Pm,
    double* __restrict__ Pb)
{
    const int t = threadIdx.x;
    const int lane = t & 63;
    const int w = t >> 6;
    const int row0 = blockIdx.x * 8;             // block owns 8 rows

    // ---- cls + labels: wave w handles rows row0 + 2w, row0 + 2w + 1
    float wcls = 0.f;
    #pragma unroll
    for (int rr = 0; rr < 2; ++rr) {
        const int r = row0 + w * 2 + rr;
        const float* Yp = Y + (size_t)r * NCLASS;
        const float* yp = y + (size_t)r * NCLASS;
        const bool has2 = lane < (NCLASS - 64);
        float Y0 = Yp[lane];
        float Y1 = has2 ? Yp[64 + lane] : -1e30f;
        float y0 = yp[lane];
        float y1 = has2 ? yp[64 + lane] : 0.f;
        float m = fmaxf(Y0, Y1);
        #pragma unroll
        for (int o = 32; o; o >>= 1) m = fmaxf(m, __shfl_xor(m, o, 64));
        float e  = __expf(Y0 - m) + (has2 ? __expf(Y1 - m) : 0.f);
        float tg = y0 * Y0 + (has2 ? y1 * Y1 : 0.f);
        #pragma unroll
        for (int o = 32; o; o >>= 1) { e += __shfl_xor(e, o, 64); tg += __shfl_xor(tg, o, 64); }
        unsigned long long b0 = __ballot(y0 > 0.5f);
        unsigned long long b1 = __ballot(has2 && (y1 > 0.5f));
        if (lane == 0) {
            int lbl = b0 ? (__ffsll((long long)b0) - 1) : (64 + __ffsll((long long)b1) - 1);
            labels[r] = lbl;
            wcls += m + __logf(e) - tg;
        }
    }

    // ---- u: quant + bal. thread t owns float t of the block's 256-float chunk
    const float x = u[(size_t)row0 * BIT + t];
    float bb = (x > 0.f) ? 1.f : ((x < 0.f) ? -1.f : 0.f);  // jnp.sign
    float d = x - bb;
    float bal = d * d;
    float rs = x;
    #pragma unroll
    for (int o = 1; o < 32; o <<= 1) rs += __shfl_xor(rs, o, 64);  // 32 lanes = one u row
    float mrow = rs * (1.f / BIT);
    float m2 = ((t & 31) == 0) ? mrow * mrow : 0.f;
    #pragma unroll
    for (int o = 32; o; o >>= 1) { m2 += __shfl_down(m2, o, 64); bal += __shfl_down(bal, o, 64); }

    __shared__ double red[4][3];
    if (lane == 0) { red[w][0] = (double)wcls; red[w][1] = (double)m2; red[w][2] = (double)bal; }
    __syncthreads();
    if (t == 0) {
        Pc[blockIdx.x] = red[0][0] + red[1][0] + red[2][0] + red[3][0];
        Pm[blockIdx.x] = red[0][1] + red[1][1] + red[2][1] + red[3][1];
        Pb[blockIdx.x] = red[0][2] + red[1][2] + red[2][2] + red[3][2];
    }
}

// ------- pairwise hash loss: bf16 MFMA, 128x128 tiles, 4 blocks/CU for barrier stagger --
__global__ __launch_bounds__(256, 4) void pair_kernel(
    const float* __restrict__ u, const int* __restrict__ labels,
    double* __restrict__ Ppos, double* __restrict__ Pneg)
{
    // closed-form triangular decode: b -> (ti, tj), ti <= tj
    const int b = blockIdx.x;
    int ti = (int)(((float)(2 * NT + 1) - sqrtf((float)((2 * NT + 1) * (2 * NT + 1) - 8 * b))) * 0.5f);
    int S = ti * (2 * NT - ti + 1) / 2;
    if (S > b) { --ti; S = ti * (2 * NT - ti + 1) / 2; }
    else { int S2 = (ti + 1) * (2 * NT - ti) / 2; if (S2 <= b) { ++ti; S = S2; } }
    const int tj = ti + (b - S);
    const int i0 = ti * BT, j0 = tj * BT;

    __shared__ __align__(16) unsigned short Us[4][256][8];   // 16 KB, conflict-free layout
    __shared__ int Ls[256];
    __shared__ float wredp[4], wredn[4];

    const int t = threadIdx.x;

    // stage: thread t owns staged row t (0..127 = A rows i0.., 128..255 = B rows j0..)
    {
        const int g = (t < BT) ? (i0 + t) : (j0 + t - BT);
        const float4* p = (const float4*)(u + (size_t)g * BIT);
        #pragma unroll
        for (int c = 0; c < 4; ++c) {
            float4 v0 = p[2 * c], v1 = p[2 * c + 1];
            s16x8 fr;
            fr[0] = (short)f2bf(v0.x); fr[1] = (short)f2bf(v0.y);
            fr[2] = (short)f2bf(v0.z); fr[3] = (short)f2bf(v0.w);
            fr[4] = (short)f2bf(v1.x); fr[5] = (short)f2bf(v1.y);
            fr[6] = (short)f2bf(v1.z); fr[7] = (short)f2bf(v1.w);
            *(s16x8*)&Us[c][t][0] = fr;
        }
        Ls[t] = labels[g];
    }
    __syncthreads();

    const int lane = t & 63;
    const int w = t >> 6;            // wave 0..3, 2x2 wave grid, 64x64 per wave
    const int wy = w >> 1, wx = w & 1;
    const int quad = lane >> 4, lr = lane & 15;

    s16x8 av[4], bv[4];
    #pragma unroll
    for (int x = 0; x < 4; ++x) {
        av[x] = *(const s16x8*)&Us[quad][wy * 64 + x * 16 + lr][0];
        bv[x] = *(const s16x8*)&Us[quad][128 + wx * 64 + x * 16 + lr][0];
    }
    int lbv[4], lav[16];
    #pragma unroll
    for (int c = 0; c < 4; ++c) lbv[c] = Ls[128 + wx * 64 + c * 16 + lr];
    #pragma unroll
    for (int a = 0; a < 4; ++a)
        #pragma unroll
        for (int r = 0; r < 4; ++r) lav[a * 4 + r] = Ls[wy * 64 + a * 16 + quad * 4 + r];

    float sp0 = 0.f, sp1 = 0.f, sn0 = 0.f, sn1 = 0.f;
    auto run = [&](auto DIAGC) {
        constexpr bool DIAG = decltype(DIAGC)::value;
        f32x4 accf[4][4];
        #pragma unroll
        for (int a = 0; a < 4; ++a)
            #pragma unroll
            for (int c = 0; c < 4; ++c)
                accf[a][c] = __builtin_amdgcn_mfma_f32_16x16x32_bf16(
                    av[a], bv[c], (f32x4){0.f, 0.f, 0.f, 0.f}, 0, 0, 0);

        #pragma unroll
        for (int a = 0; a < 4; ++a) {
            #pragma unroll
            for (int c = 0; c < 4; ++c) {
                const int lb = lbv[c];
                #pragma unroll
                for (int r = 0; r < 4; ++r) {
                    const float v = accf[a][c][r];   // col=lane&15, row=quad*4+reg
                    const bool sim = (lav[a * 4 + r] == lb);
                    float hv = 0.5f * v;             // theta
                    float e  = exp2f(-1.44269504f * fabsf(hv));
                    float lt = 0.69314718f * __log2f(1.f + e);
                    float tp = fmaxf(-hv, 0.f) + lt; // softplus(th) - th
                    float tn = tp + hv;              // softplus(th)
                    if (DIAG) {
                        const int lrow = wy * 64 + a * 16 + quad * 4 + r;
                        const int lcol = wx * 64 + c * 16 + lr;
                        const bool keep = lcol > lrow;   // strict upper triangle
                        tp = keep ? tp : 0.f;
                        tn = keep ? tn : 0.f;
                    }
                    float up = sim ? tp : 0.f;
                    float un = sim ? 0.f : tn;
                    if (r & 1) { sp1 += up; sn1 += un; }
                    else       { sp0 += up; sn0 += un; }
                }
            }
        }
    };
    if (ti == tj) run(std::integral_constant<bool, true>{});
    else          run(std::integral_constant<bool, false>{});

    float sp = sp0 + sp1, sn = sn0 + sn1;
    #pragma unroll
    for (int o = 32; o; o >>= 1) { sp += __shfl_down(sp, o, 64); sn += __shfl_down(sn, o, 64); }
    if (lane == 0) { wredp[w] = sp; wredn[w] = sn; }
    __syncthreads();
    if (t == 0) {
        Ppos[b] = (double)(wredp[0] + wredp[1] + wredp[2] + wredp[3]);
        Pneg[b] = (double)(wredn[0] + wredn[1] + wredn[2] + wredn[3]);
    }
}

// ---------------- finalize: histogram from labels + scales + reduce partials -----------
__global__ __launch_bounds__(256) void fin_kernel(
    const int* __restrict__ labels, const double* __restrict__ Ppos,
    const double* __restrict__ Pneg, const double* __restrict__ Pc,
    const double* __restrict__ Pm, const double* __restrict__ Pb, float* __restrict__ out)
{
    __shared__ int h[128];
    __shared__ double red[4][5];
    __shared__ double scd[2];
    const int t = threadIdx.x;
    const int lane = t & 63;
    const int w = t >> 6;

    if (t < 128) h[t] = 0;
    __syncthreads();
    #pragma unroll
    for (int k = 0; k < 32; ++k) atomicAdd(&h[labels[t + k * 256]], 1);
    __syncthreads();

    if (w == 0) {                 // wave 0: simsum -> scales
        long long c0 = (lane < NCLASS) ? h[lane] : 0;
        long long c1 = (lane + 64 < NCLASS) ? h[lane + 64] : 0;
        long long ss = c0 * c0 + c1 * c1;
        #pragma unroll
        for (int o = 32; o; o >>= 1) ss += __shfl_xor(ss, o, 64);
        if (lane == 0) {
            double s1 = (double)ss - (double)N;
            double s0 = (double)N * (double)N - (double)ss;
            if (s0 == 0.0) s0 = 1.0;
            if (s1 == 0.0) s1 = 1.0;
            double s = s0 + s1;
            scd[0] = s / s1;      // spos
            scd[1] = s / s0;      // sneg
        }
    }

    double p0 = 0, p1 = 0, cc = 0, mm = 0, bb = 0;
    for (int i = t; i < NPAIRBLK; i += 256) { p0 += Ppos[i]; p1 += Pneg[i]; }
    for (int i = t; i < NPREP; i += 256)    { cc += Pc[i]; mm += Pm[i]; bb += Pb[i]; }
    #pragma unroll
    for (int o = 32; o; o >>= 1) {
        p0 += __shfl_down(p0, o, 64); p1 += __shfl_down(p1, o, 64);
        cc += __shfl_down(cc, o, 64); mm += __shfl_down(mm, o, 64);
        bb += __shfl_down(bb, o, 64);
    }
    if (lane == 0) { red[w][0] = p0; red[w][1] = p1; red[w][2] = cc; red[w][3] = mm; red[w][4] = bb; }
    __syncthreads();
    if (t == 0) {
        double a_pos = red[0][0] + red[1][0] + red[2][0] + red[3][0];
        double a_neg = red[0][1] + red[1][1] + red[2][1] + red[3][1];
        double a_cls = red[0][2] + red[1][2] + red[2][2] + red[3][2];
        double a_m2  = red[0][3] + red[1][3] + red[2][3] + red[3][3];
        double a_bal = red[0][4] + red[1][4] + red[2][4] + red[3][4];
        double pairsum = scd[0] * a_pos + scd[1] * a_neg;
        double lik   = 2.0 * pairsum / ((double)N * (double)(N - 1));
        double cls   = a_cls / (double)N;
        double quant = ALPHA * (a_m2 / (double)N);
        double bal   = GAMMA * (a_bal / ((double)N * (double)BIT));
        out[0] = (float)(lik + BEITA * cls + quant + bal);
    }
}

extern "C" void kernel_launch(void* const* d_in, const int* in_sizes, int n_in,
                              void* d_out, int out_size, void* d_ws, size_t ws_size,
                              hipStream_t stream) {
    const float* u = (const float*)d_in[0];   // [N, BIT]
    const float* Y = (const float*)d_in[1];   // [N, NCLASS]
    const float* y = (const float*)d_in[2];   // [N, NCLASS] one-hot
    float* out = (float*)d_out;

    char* ws = (char*)d_ws;
    int*    labels = (int*)(ws + 1024);
    double* Ppos   = (double*)(ws + 40960);
    double* Pneg   = (double*)(ws + 61440);
    double* Pc     = (double*)(ws + 81920);
    double* Pm     = (double*)(ws + 90112);
    double* Pb     = (double*)(ws + 98304);

    // no memset: every ws word consumed is written unconditionally earlier in the chain
    prep_kernel<<<NPREP, 256, 0, stream>>>(u, Y, y, labels, Pc, Pm, Pb);
    pair_kernel<<<NPAIRBLK, 256, 0, stream>>>(u, labels, Ppos, Pneg);
    fin_kernel<<<1, 256, 0, stream>>>(labels, Ppos, Pneg, Pc, Pm, Pb, out);
}